// Round 8
// baseline (589.539 us; speedup 1.0000x reference)
//
#include <hip/hip_runtime.h>

#define D_IN 50
#define LN_EPS 1e-5f
#define BSH 8           // 256 nodes per bucket
#define MAXB 512        // max buckets (N <= 131072)

typedef __bf16 bf16_t;
typedef bf16_t bf16x8 __attribute__((ext_vector_type(8)));
typedef bf16_t bf16x4 __attribute__((ext_vector_type(4)));
typedef bf16_t bf16x2 __attribute__((ext_vector_type(2)));
typedef float f32x4_t __attribute__((ext_vector_type(4)));

// accumulate 4 u32 (8 bf16) into lo/hi float banks; bf16->f32 is a shift
#define ACC8(r, L, H)                                                        \
    {                                                                        \
        L[0] += __uint_as_float((r).x << 16);                                \
        H[0] += __uint_as_float((r).x & 0xffff0000u);                        \
        L[1] += __uint_as_float((r).y << 16);                                \
        H[1] += __uint_as_float((r).y & 0xffff0000u);                        \
        L[2] += __uint_as_float((r).z << 16);                                \
        H[2] += __uint_as_float((r).z & 0xffff0000u);                        \
        L[3] += __uint_as_float((r).w << 16);                                \
        H[3] += __uint_as_float((r).w & 0xffff0000u);                        \
    }

// ---------------------------------------------------------------- CSR build
__global__ void bucket_hist_k(const int* __restrict__ dst, int* __restrict__ bcnt,
                              int e, int nb) {
    __shared__ int lh[MAXB];
    int t = threadIdx.x;
    for (int i = t; i < nb; i += 256) lh[i] = 0;
    __syncthreads();
    for (int i = blockIdx.x * 256 + t; i < e; i += gridDim.x * 256)
        atomicAdd(&lh[dst[i] >> BSH], 1);
    __syncthreads();
    for (int i = t; i < nb; i += 256) {
        int c = lh[i];
        if (c) atomicAdd(&bcnt[i * 16], c);
    }
}

__global__ void bscan_k(const int* __restrict__ bcnt, int* __restrict__ boff,
                        int* __restrict__ bpos, int nb, int e) {
    __shared__ int l[MAXB];
    int t = threadIdx.x;
    l[t] = (t < nb) ? bcnt[t * 16] : 0;
    __syncthreads();
    for (int off = 1; off < MAXB; off <<= 1) {
        int v = (t >= off) ? l[t - off] : 0;
        __syncthreads();
        l[t] += v;
        __syncthreads();
    }
    int excl = (t > 0) ? l[t - 1] : 0;
    if (t < nb) { boff[t] = excl; bpos[t * 16] = excl; }
    if (t == 0) boff[nb] = e;
}

__global__ void scatter_k(const int* __restrict__ src, const int* __restrict__ dst,
                          int* __restrict__ bpos, unsigned* __restrict__ pool,
                          int e, int nb) {
    __shared__ int lh[MAXB];
    __shared__ int lcur[MAXB];
    int t = threadIdx.x;
    for (int i = t; i < nb; i += 256) lh[i] = 0;
    __syncthreads();
    int chunk = (e + gridDim.x - 1) / gridDim.x;
    int s = blockIdx.x * chunk;
    int en = min(e, s + chunk);
    for (int i = s + t; i < en; i += 256)
        atomicAdd(&lh[dst[i] >> BSH], 1);
    __syncthreads();
    for (int i = t; i < nb; i += 256) {
        int c = lh[i];
        lcur[i] = c ? atomicAdd(&bpos[i * 16], c) : 0;
    }
    __syncthreads();
    for (int i = s + t; i < en; i += 256) {
        int d = dst[i];
        int p = atomicAdd(&lcur[d >> BSH], 1);
        pool[p] = (unsigned)src[i] | ((unsigned)(d & 255) << 17);
    }
}

// fused: per-bucket node histogram + LDS exclusive scan -> rp directly
// (bucket segments are contiguous, so rp = boff[b] + local exclusive scan)
__global__ void nhist_rp_k(const unsigned* __restrict__ pool, const int* __restrict__ boff,
                           int* __restrict__ rp, int n) {
    __shared__ int lc[256];
    __shared__ int ls[256];
    int b = blockIdx.x, t = threadIdx.x;
    lc[t] = 0;
    __syncthreads();
    int s = boff[b], e = boff[b + 1];
    for (int i = s + t; i < e; i += 256) atomicAdd(&lc[pool[i] >> 17], 1);
    __syncthreads();
    int v = lc[t];
    ls[t] = v;
    __syncthreads();
    for (int off = 1; off < 256; off <<= 1) {
        int x = (t >= off) ? ls[t - off] : 0;
        __syncthreads();
        ls[t] += x;
        __syncthreads();
    }
    int excl = ls[t] - v;
    int nd = (b << BSH) + t;
    if (nd < n) rp[nd] = s + excl;
    if (nd == n - 1) rp[n] = e;
}

__global__ void cfill_k(const unsigned* __restrict__ pool, const int* __restrict__ boff,
                        const int* __restrict__ rp, int* __restrict__ col, int n) {
    __shared__ int lpos[256];
    int b = blockIdx.x, t = threadIdx.x;
    int nd = (b << BSH) + t;
    lpos[t] = (nd < n) ? rp[nd] : 0;
    __syncthreads();
    int s = boff[b], e = boff[b + 1];
    for (int i = s + t; i < e; i += 256) {
        unsigned pk = pool[i];
        int slot = atomicAdd(&lpos[pk >> 17], 1);
        col[slot] = (int)(pk & 0x1FFFFu);
    }
}

// -------------------------------------------------------------- converters
struct ConvDesc { const float* w; bf16_t* o; int kin; int kpad; };
struct ConvArgs { ConvDesc d[8]; };

// fused weight transpose + x conversion (y=0: x, y=1: weights)
__global__ void conv_all_k(ConvArgs args, const float* __restrict__ x,
                           bf16_t* __restrict__ xb, int n) {
    if (blockIdx.y == 0) {
        int i = blockIdx.x * 256 + threadIdx.x;
        if (i < n * 64) {
            int node = i >> 6, k = i & 63;
            xb[i] = (k < D_IN) ? (bf16_t)x[node * D_IN + k] : (bf16_t)0.f;
        }
    } else {
        int d_idx = blockIdx.x >> 6;
        if (d_idx < 8) {
            ConvDesc d = args.d[d_idx];
            int i = (blockIdx.x & 63) * 256 + threadIdx.x;
            int tot = 128 * d.kpad;
            if (i < tot) {
                int nn = i / d.kpad, k = i - nn * d.kpad;
                d.o[i] = (bf16_t)((k < d.kin) ? d.w[(size_t)k * 128 + nn] : 0.f);
            }
        }
    }
}

// ------------------------------------------------------------- aggregation
__global__ void agg_bf64_k(const bf16_t* __restrict__ feat, const int* __restrict__ rp,
                           const int* __restrict__ col, bf16_t* __restrict__ mean, int n) {
    int wid = (blockIdx.x * blockDim.x + threadIdx.x) >> 6;
    int lane = threadIdx.x & 63;
    if (wid >= n) return;
    int start = rp[wid], end = rp[wid + 1];
    int lc = lane & 7;
    int g = lane >> 3;
    float aL[4], aH[4], bL[4], bH[4];
#pragma unroll
    for (int k = 0; k < 4; k++) { aL[k] = aH[k] = bL[k] = bH[k] = 0.f; }
    int e = start + g;
    for (; e + 8 < end; e += 16) {
        uint4 r0 = *(const uint4*)(feat + (size_t)col[e] * 64 + lc * 8);
        uint4 r1 = *(const uint4*)(feat + (size_t)col[e + 8] * 64 + lc * 8);
        ACC8(r0, aL, aH);
        ACC8(r1, bL, bH);
    }
    for (; e < end; e += 8) {
        uint4 r0 = *(const uint4*)(feat + (size_t)col[e] * 64 + lc * 8);
        ACC8(r0, aL, aH);
    }
#pragma unroll
    for (int k = 0; k < 4; k++) { aL[k] += bL[k]; aH[k] += bH[k]; }
#pragma unroll
    for (int off = 8; off < 64; off <<= 1) {
#pragma unroll
        for (int k = 0; k < 4; k++) {
            aL[k] += __shfl_xor(aL[k], off);
            aH[k] += __shfl_xor(aH[k], off);
        }
    }
    int c = end - start;
    float invc = 1.f / (float)(c > 0 ? c : 1);
    if (lane < 8) {
        bf16x8 o;
#pragma unroll
        for (int k = 0; k < 4; k++) {
            o[2 * k] = (bf16_t)(aL[k] * invc);
            o[2 * k + 1] = (bf16_t)(aH[k] * invc);
        }
        *(bf16x8*)(mean + (size_t)wid * 64 + lc * 8) = o;
    }
}

__global__ void agg_bf128_k(const bf16_t* __restrict__ feat, const int* __restrict__ rp,
                            const int* __restrict__ col, bf16_t* __restrict__ mean, int n) {
    int wid = (blockIdx.x * blockDim.x + threadIdx.x) >> 6;
    int lane = threadIdx.x & 63;
    if (wid >= n) return;
    int start = rp[wid], end = rp[wid + 1];
    int lc = lane & 15;
    int g = lane >> 4;
    float aL[4], aH[4], bL[4], bH[4];
#pragma unroll
    for (int k = 0; k < 4; k++) { aL[k] = aH[k] = bL[k] = bH[k] = 0.f; }
    int e = start + g;
    for (; e + 4 < end; e += 8) {
        uint4 r0 = *(const uint4*)(feat + (size_t)col[e] * 128 + lc * 8);
        uint4 r1 = *(const uint4*)(feat + (size_t)col[e + 4] * 128 + lc * 8);
        ACC8(r0, aL, aH);
        ACC8(r1, bL, bH);
    }
    for (; e < end; e += 4) {
        uint4 r0 = *(const uint4*)(feat + (size_t)col[e] * 128 + lc * 8);
        ACC8(r0, aL, aH);
    }
#pragma unroll
    for (int k = 0; k < 4; k++) { aL[k] += bL[k]; aH[k] += bH[k]; }
#pragma unroll
    for (int off = 16; off < 64; off <<= 1) {
#pragma unroll
        for (int k = 0; k < 4; k++) {
            aL[k] += __shfl_xor(aL[k], off);
            aH[k] += __shfl_xor(aH[k], off);
        }
    }
    int c = end - start;
    float invc = 1.f / (float)(c > 0 ? c : 1);
    if (lane < 16) {
        bf16x8 o;
#pragma unroll
        for (int k = 0; k < 4; k++) {
            o[2 * k] = (bf16_t)(aL[k] * invc);
            o[2 * k + 1] = (bf16_t)(aH[k] * invc);
        }
        *(bf16x8*)(mean + (size_t)wid * 128 + lc * 8) = o;
    }
}

// ------------------------------------------------- fused SAGE linear (MFMA)
template <int KPAD, bool DUAL, bool ACC>
__global__ __launch_bounds__(256) void mfma_gemm_k(
    const bf16_t* __restrict__ A, const bf16_t* __restrict__ B,
    const bf16_t* __restrict__ WlT, const bf16_t* __restrict__ WrT,
    const float* __restrict__ bias,
    bf16_t* __restrict__ out, float2* __restrict__ partials, int M) {
    constexpr int KC = KPAD / 32;
    constexpr int WELE = 8 * KC * 64 * 8;
    __shared__ bf16_t lwl[WELE];
    __shared__ bf16_t lwr[DUAL ? WELE : 8];

    const int tid = threadIdx.x;
    for (int ch = tid; ch < 8 * KC * 64; ch += 256) {
        int nt = ch / (KC * 64);
        int rem = ch - nt * (KC * 64);
        int c = rem >> 6;
        int ln = rem & 63;
        int m = ln & 15, q = ln >> 4;
        size_t srcoff = (size_t)(nt * 16 + m) * KPAD + c * 32 + q * 8;
        *(bf16x8*)&lwl[ch * 8] = *(const bf16x8*)(WlT + srcoff);
        if (DUAL) *(bf16x8*)&lwr[ch * 8] = *(const bf16x8*)(WrT + srcoff);
    }
    __syncthreads();

    const int wid = blockIdx.x * 4 + (tid >> 6);
    const int lane = tid & 63;
    const int row0 = wid * 32;
    if (row0 >= M) return;
    const int m = lane & 15;
    const int q = lane >> 4;

    bf16x8 af[2][KC], bfr[DUAL ? 2 : 1][DUAL ? KC : 1];
#pragma unroll
    for (int s = 0; s < 2; s++) {
        const bf16_t* ar = A + (size_t)(row0 + s * 16 + m) * KPAD + q * 8;
#pragma unroll
        for (int c = 0; c < KC; c++) af[s][c] = *(const bf16x8*)(ar + c * 32);
        if (DUAL) {
            const bf16_t* br = B + (size_t)(row0 + s * 16 + m) * KPAD + q * 8;
#pragma unroll
            for (int c = 0; c < KC; c++) bfr[s][c] = *(const bf16x8*)(br + c * 32);
        }
    }

    float lsum = 0.f, lsum2 = 0.f;
#pragma unroll
    for (int nt = 0; nt < 8; nt++) {
        f32x4_t acc0 = {0.f, 0.f, 0.f, 0.f};
        f32x4_t acc1 = {0.f, 0.f, 0.f, 0.f};
#pragma unroll
        for (int c = 0; c < KC; c++) {
            bf16x8 w = *(const bf16x8*)&lwl[((nt * KC + c) * 64 + lane) * 8];
            acc0 = __builtin_amdgcn_mfma_f32_16x16x32_bf16(af[0][c], w, acc0, 0, 0, 0);
            acc1 = __builtin_amdgcn_mfma_f32_16x16x32_bf16(af[1][c], w, acc1, 0, 0, 0);
        }
        if (DUAL) {
#pragma unroll
            for (int c = 0; c < KC; c++) {
                bf16x8 w = *(const bf16x8*)&lwr[((nt * KC + c) * 64 + lane) * 8];
                acc0 = __builtin_amdgcn_mfma_f32_16x16x32_bf16(bfr[0][c], w, acc0, 0, 0, 0);
                acc1 = __builtin_amdgcn_mfma_f32_16x16x32_bf16(bfr[1][c], w, acc1, 0, 0, 0);
            }
        }
        float bv = bias ? bias[nt * 16 + m] : 0.f;
#pragma unroll
        for (int s = 0; s < 2; s++) {
            f32x4_t* ap = (s == 0) ? &acc0 : &acc1;
#pragma unroll
            for (int r = 0; r < 4; r++) {
                int row = row0 + s * 16 + q * 4 + r;
                if (row < M) {
                    float o = (*ap)[r] + bv;
                    out[(size_t)row * 128 + nt * 16 + m] = (bf16_t)o;
                    if (ACC) { lsum += o; lsum2 += o * o; }
                }
            }
        }
    }
    if (ACC) {
        for (int off = 32; off > 0; off >>= 1) {
            lsum += __shfl_down(lsum, off);
            lsum2 += __shfl_down(lsum2, off);
        }
        if (lane == 0) partials[wid] = make_float2(lsum, lsum2);
    }
}

// Layer-1 triple: PRE = mean@Wl1 + xb@Wr1 + b1 (LN partials),
// C1 = xb@Ws1, C2 = xb@Ws2. KPAD=64.
__global__ __launch_bounds__(256) void mfma_gemm3_k(
    const bf16_t* __restrict__ A, const bf16_t* __restrict__ B,
    const bf16_t* __restrict__ WlT, const bf16_t* __restrict__ WrT,
    const bf16_t* __restrict__ Ws1T, const bf16_t* __restrict__ Ws2T,
    const float* __restrict__ bias,
    bf16_t* __restrict__ outP, bf16_t* __restrict__ outC1, bf16_t* __restrict__ outC2,
    float2* __restrict__ partials, int M) {
    constexpr int KC = 2;
    constexpr int WELE = 8 * KC * 64 * 8;
    __shared__ bf16_t lwl[WELE];
    __shared__ bf16_t lwr[WELE];
    __shared__ bf16_t ls1[WELE];
    __shared__ bf16_t ls2[WELE];

    const int tid = threadIdx.x;
    for (int ch = tid; ch < 8 * KC * 64; ch += 256) {
        int nt = ch / (KC * 64);
        int rem = ch - nt * (KC * 64);
        int c = rem >> 6;
        int ln = rem & 63;
        int m = ln & 15, q = ln >> 4;
        size_t srcoff = (size_t)(nt * 16 + m) * 64 + c * 32 + q * 8;
        *(bf16x8*)&lwl[ch * 8] = *(const bf16x8*)(WlT + srcoff);
        *(bf16x8*)&lwr[ch * 8] = *(const bf16x8*)(WrT + srcoff);
        *(bf16x8*)&ls1[ch * 8] = *(const bf16x8*)(Ws1T + srcoff);
        *(bf16x8*)&ls2[ch * 8] = *(const bf16x8*)(Ws2T + srcoff);
    }
    __syncthreads();

    const int wid = blockIdx.x * 4 + (tid >> 6);
    const int lane = tid & 63;
    const int row0 = wid * 32;
    if (row0 >= M) return;
    const int m = lane & 15;
    const int q = lane >> 4;

    bf16x8 af[2][KC], bfr[2][KC];
#pragma unroll
    for (int s = 0; s < 2; s++) {
        const bf16_t* ar = A + (size_t)(row0 + s * 16 + m) * 64 + q * 8;
        const bf16_t* br = B + (size_t)(row0 + s * 16 + m) * 64 + q * 8;
#pragma unroll
        for (int c = 0; c < KC; c++) {
            af[s][c] = *(const bf16x8*)(ar + c * 32);
            bfr[s][c] = *(const bf16x8*)(br + c * 32);
        }
    }

    float lsum = 0.f, lsum2 = 0.f;
#pragma unroll
    for (int nt = 0; nt < 8; nt++) {
        f32x4_t aP0 = {0.f, 0.f, 0.f, 0.f}, aP1 = {0.f, 0.f, 0.f, 0.f};
        f32x4_t a10 = {0.f, 0.f, 0.f, 0.f}, a11 = {0.f, 0.f, 0.f, 0.f};
        f32x4_t a20 = {0.f, 0.f, 0.f, 0.f}, a21 = {0.f, 0.f, 0.f, 0.f};
#pragma unroll
        for (int c = 0; c < KC; c++) {
            int wi = ((nt * KC + c) * 64 + lane) * 8;
            bf16x8 wl = *(const bf16x8*)&lwl[wi];
            bf16x8 wr = *(const bf16x8*)&lwr[wi];
            bf16x8 w1 = *(const bf16x8*)&ls1[wi];
            bf16x8 w2 = *(const bf16x8*)&ls2[wi];
            aP0 = __builtin_amdgcn_mfma_f32_16x16x32_bf16(af[0][c], wl, aP0, 0, 0, 0);
            aP1 = __builtin_amdgcn_mfma_f32_16x16x32_bf16(af[1][c], wl, aP1, 0, 0, 0);
            aP0 = __builtin_amdgcn_mfma_f32_16x16x32_bf16(bfr[0][c], wr, aP0, 0, 0, 0);
            aP1 = __builtin_amdgcn_mfma_f32_16x16x32_bf16(bfr[1][c], wr, aP1, 0, 0, 0);
            a10 = __builtin_amdgcn_mfma_f32_16x16x32_bf16(bfr[0][c], w1, a10, 0, 0, 0);
            a11 = __builtin_amdgcn_mfma_f32_16x16x32_bf16(bfr[1][c], w1, a11, 0, 0, 0);
            a20 = __builtin_amdgcn_mfma_f32_16x16x32_bf16(bfr[0][c], w2, a20, 0, 0, 0);
            a21 = __builtin_amdgcn_mfma_f32_16x16x32_bf16(bfr[1][c], w2, a21, 0, 0, 0);
        }
        float bv = bias[nt * 16 + m];
#pragma unroll
        for (int s = 0; s < 2; s++) {
            f32x4_t* pP = (s == 0) ? &aP0 : &aP1;
            f32x4_t* p1 = (s == 0) ? &a10 : &a11;
            f32x4_t* p2 = (s == 0) ? &a20 : &a21;
#pragma unroll
            for (int r = 0; r < 4; r++) {
                int row = row0 + s * 16 + q * 4 + r;
                if (row < M) {
                    float o = (*pP)[r] + bv;
                    size_t oi = (size_t)row * 128 + nt * 16 + m;
                    outP[oi] = (bf16_t)o;
                    outC1[oi] = (bf16_t)(*p1)[r];
                    outC2[oi] = (bf16_t)(*p2)[r];
                    lsum += o; lsum2 += o * o;
                }
            }
        }
    }
    for (int off = 32; off > 0; off >>= 1) {
        lsum += __shfl_down(lsum, off);
        lsum2 += __shfl_down(lsum2, off);
    }
    if (lane == 0) partials[wid] = make_float2(lsum, lsum2);
}

// --------------------------------------------- LN (graph mode) + PReLU (+skip)
// Stats reduced in-block from partials (no separate reduce dispatch).
template <int MODE>
__global__ void ln_prelu_k(const bf16_t* __restrict__ pre, const bf16_t* __restrict__ h1in,
                           const bf16_t* __restrict__ s,
                           const float* __restrict__ lnw, const float* __restrict__ lnb,
                           const float* __restrict__ a_ptr,
                           const float2* __restrict__ partials, int nparts,
                           void* __restrict__ out0v, void* __restrict__ out1v, int total) {
    __shared__ float w1[4], w2[4];
    int tid = threadIdx.x;
    float ps = 0.f, ps2 = 0.f;
    for (int i = tid; i < nparts; i += 256) {
        float2 p = partials[i];
        ps += p.x;
        ps2 += p.y;
    }
    for (int off = 32; off > 0; off >>= 1) {
        ps += __shfl_down(ps, off);
        ps2 += __shfl_down(ps2, off);
    }
    int wave = tid >> 6, lane = tid & 63;
    if (lane == 0) { w1[wave] = ps; w2[wave] = ps2; }
    __syncthreads();
    float sum = w1[0] + w1[1] + w1[2] + w1[3];
    float sum2 = w2[0] + w2[1] + w2[2] + w2[3];

    int i = blockIdx.x * blockDim.x + tid;
    if (i * 4 >= total) return;
    float cinv = 1.0f / (float)total;
    float mf = sum * cinv;
    float var = sum2 * cinv - mf * mf;
    float stdv = sqrtf(var > 0.f ? var : 0.f);
    float scale = 1.0f / (stdv + LN_EPS);
    float a = a_ptr[0];
    int c4 = i & 31;
    float4 w = ((const float4*)lnw)[c4];
    float4 b = ((const float4*)lnb)[c4];
    bf16x4 p4 = ((const bf16x4*)pre)[i];
    float4 h;
    h.x = ((float)p4.x - mf) * scale * w.x + b.x;
    h.y = ((float)p4.y - mf) * scale * w.y + b.y;
    h.z = ((float)p4.z - mf) * scale * w.z + b.z;
    h.w = ((float)p4.w - mf) * scale * w.w + b.w;
    h.x = h.x >= 0.f ? h.x : a * h.x;
    h.y = h.y >= 0.f ? h.y : a * h.y;
    h.z = h.z >= 0.f ? h.z : a * h.z;
    h.w = h.w >= 0.f ? h.w : a * h.w;
    if (MODE == 1) {
        bf16x4 hb;
        hb.x = (bf16_t)h.x; hb.y = (bf16_t)h.y; hb.z = (bf16_t)h.z; hb.w = (bf16_t)h.w;
        ((bf16x4*)out0v)[i] = hb;
        bf16x4 sv = ((const bf16x4*)s)[i];
        bf16x4 tb;
        tb.x = (bf16_t)(h.x + (float)sv.x); tb.y = (bf16_t)(h.y + (float)sv.y);
        tb.z = (bf16_t)(h.z + (float)sv.z); tb.w = (bf16_t)(h.w + (float)sv.w);
        ((bf16x4*)out1v)[i] = tb;
    } else if (MODE == 2) {
        bf16x4 hv = ((const bf16x4*)h1in)[i];
        bf16x4 sv = ((const bf16x4*)s)[i];
        bf16x4 tb;
        tb.x = (bf16_t)((float)hv.x + h.x + (float)sv.x);
        tb.y = (bf16_t)((float)hv.y + h.y + (float)sv.y);
        tb.z = (bf16_t)((float)hv.z + h.z + (float)sv.z);
        tb.w = (bf16_t)((float)hv.w + h.w + (float)sv.w);
        ((bf16x4*)out0v)[i] = tb;
    } else {
        ((float4*)out0v)[i] = h;
    }
}

// ------------------------------------------------------------------ launch
extern "C" void kernel_launch(void* const* d_in, const int* in_sizes, int n_in,
                              void* d_out, int out_size, void* d_ws, size_t ws_size,
                              hipStream_t stream) {
    const float* x    = (const float*)d_in[0];
    const int*   esrc = (const int*)d_in[1];
    const int*   edst = (const int*)d_in[2];
    const float* Wl1  = (const float*)d_in[3];
    const float* Wr1  = (const float*)d_in[4];
    const float* b1   = (const float*)d_in[5];
    const float* Wl2  = (const float*)d_in[6];
    const float* Wr2  = (const float*)d_in[7];
    const float* b2   = (const float*)d_in[8];
    const float* Wl3  = (const float*)d_in[9];
    const float* Wr3  = (const float*)d_in[10];
    const float* b3   = (const float*)d_in[11];
    const float* Ws1  = (const float*)d_in[12];
    const float* Ws2  = (const float*)d_in[13];
    const float* lnw1 = (const float*)d_in[14];
    const float* lnb1 = (const float*)d_in[15];
    const float* lnw2 = (const float*)d_in[16];
    const float* lnb2 = (const float*)d_in[17];
    const float* lnw3 = (const float*)d_in[18];
    const float* lnb3 = (const float*)d_in[19];
    const float* a1   = (const float*)d_in[20];
    const float* a2   = (const float*)d_in[21];
    const float* a3   = (const float*)d_in[22];

    const int N = in_sizes[0] / D_IN;
    const int E = in_sizes[1];
    const int NB = (N + 255) >> BSH;

    char* ws = (char*)d_ws;
    size_t off = 0;
    auto alloc = [&](size_t bytes) -> void* {
        void* p = ws + off;
        off += (bytes + 255) & ~(size_t)255;
        return p;
    };
    bf16_t* xb   = (bf16_t*)alloc((size_t)N * 64 * 2);
    bf16_t* mean = (bf16_t*)alloc((size_t)N * 128 * 2);
    bf16_t* PRE  = (bf16_t*)alloc((size_t)N * 128 * 2);
    bf16_t* C1   = (bf16_t*)alloc((size_t)N * 128 * 2);
    bf16_t* C2   = (bf16_t*)alloc((size_t)N * 128 * 2);
    bf16_t* h1b  = (bf16_t*)alloc((size_t)N * 128 * 2);
    bf16_t* TB   = (bf16_t*)alloc((size_t)N * 128 * 2);
    bf16_t* WT   = (bf16_t*)alloc((size_t)(4 * 128 * 64 + 4 * 128 * 128) * 2);
    int* rp   = (int*)alloc((size_t)(N + 1) * 4);
    int* col  = (int*)alloc((size_t)E * 4);
    int* bcnt = (int*)alloc((size_t)MAXB * 16 * 4);
    int* boff = (int*)alloc((size_t)(MAXB + 1) * 4);
    int* bpos = (int*)alloc((size_t)MAXB * 16 * 4);
    unsigned* pool = (unsigned*)alloc((size_t)E * 4);
    const int tiles = (N + 31) / 32;
    float2* partials = (float2*)alloc((size_t)tiles * 8);

    bf16_t* Wl1T = WT;
    bf16_t* Wr1T = Wl1T + 128 * 64;
    bf16_t* Ws1T = Wr1T + 128 * 64;
    bf16_t* Ws2T = Ws1T + 128 * 64;
    bf16_t* Wl2T = Ws2T + 128 * 64;
    bf16_t* Wr2T = Wl2T + 128 * 128;
    bf16_t* Wl3T = Wr2T + 128 * 128;
    bf16_t* Wr3T = Wl3T + 128 * 128;

    hipMemsetAsync(bcnt, 0, (size_t)MAXB * 16 * 4, stream);

    // --- bucketed CSR build (5 kernels)
    bucket_hist_k<<<256, 256, 0, stream>>>(edst, bcnt, E, NB);
    bscan_k<<<1, MAXB, 0, stream>>>(bcnt, boff, bpos, NB, E);
    scatter_k<<<256, 256, 0, stream>>>(esrc, edst, bpos, pool, E, NB);
    nhist_rp_k<<<NB, 256, 0, stream>>>(pool, boff, rp, N);
    cfill_k<<<NB, 256, 0, stream>>>(pool, boff, rp, col, N);

    // --- fused weight/feature conversion (1 kernel)
    ConvArgs ca;
    ca.d[0] = {Wl1, Wl1T, 50, 64};
    ca.d[1] = {Wr1, Wr1T, 50, 64};
    ca.d[2] = {Ws1, Ws1T, 50, 64};
    ca.d[3] = {Ws2, Ws2T, 50, 64};
    ca.d[4] = {Wl2, Wl2T, 128, 128};
    ca.d[5] = {Wr2, Wr2T, 128, 128};
    ca.d[6] = {Wl3, Wl3T, 128, 128};
    ca.d[7] = {Wr3, Wr3T, 128, 128};
    int convx = (N * 64 + 255) / 256;
    if (convx < 512) convx = 512;
    conv_all_k<<<dim3(convx, 2), 256, 0, stream>>>(ca, x, xb, N);

    const int aggBlocks = ((N * 64) + 255) / 256;
    const int gemmBlocks = (tiles + 3) / 4;
    const int lnBlocks = (N * 128 / 4 + 255) / 256;
    const int total = N * 128;

    // ---- layer 1
    agg_bf64_k<<<aggBlocks, 256, 0, stream>>>(xb, rp, col, mean, N);
    mfma_gemm3_k<<<gemmBlocks, 256, 0, stream>>>(
        mean, xb, Wl1T, Wr1T, Ws1T, Ws2T, b1, PRE, C1, C2, partials, N);
    ln_prelu_k<1><<<lnBlocks, 256, 0, stream>>>(
        PRE, nullptr, C1, lnw1, lnb1, a1, partials, tiles, h1b, TB, total);

    // ---- layer 2
    agg_bf128_k<<<aggBlocks, 256, 0, stream>>>(TB, rp, col, mean, N);
    mfma_gemm_k<128, true, true><<<gemmBlocks, 256, 0, stream>>>(
        mean, TB, Wl2T, Wr2T, b2, PRE, partials, N);
    ln_prelu_k<2><<<lnBlocks, 256, 0, stream>>>(
        PRE, h1b, C2, lnw2, lnb2, a2, partials, tiles, TB, nullptr, total);

    // ---- layer 3
    agg_bf128_k<<<aggBlocks, 256, 0, stream>>>(TB, rp, col, mean, N);
    mfma_gemm_k<128, true, true><<<gemmBlocks, 256, 0, stream>>>(
        mean, TB, Wl3T, Wr3T, b3, PRE, partials, N);
    ln_prelu_k<3><<<lnBlocks, 256, 0, stream>>>(
        PRE, nullptr, nullptr, lnw3, lnb3, a3, partials, tiles, d_out, nullptr, total);
}

// Round 9
// 546.527 us; speedup vs baseline: 1.0787x; 1.0787x over previous
//
#include <hip/hip_runtime.h>

#define D_IN 50
#define LN_EPS 1e-5f
#define BSH 8           // 256 nodes per bucket
#define MAXB 512        // max buckets (N <= 131072)

typedef __bf16 bf16_t;
typedef bf16_t bf16x8 __attribute__((ext_vector_type(8)));
typedef bf16_t bf16x4 __attribute__((ext_vector_type(4)));
typedef bf16_t bf16x2 __attribute__((ext_vector_type(2)));
typedef float f32x4_t __attribute__((ext_vector_type(4)));
typedef float f32x2_t __attribute__((ext_vector_type(2)));

// accumulate 4 u32 (8 bf16) into 4 packed float2 accumulators (v_pk_add_f32)
#define ACCP(r, A)                                                            \
    {                                                                         \
        A[0] += (f32x2_t){__uint_as_float((r).x << 16),                       \
                          __uint_as_float((r).x & 0xffff0000u)};              \
        A[1] += (f32x2_t){__uint_as_float((r).y << 16),                       \
                          __uint_as_float((r).y & 0xffff0000u)};              \
        A[2] += (f32x2_t){__uint_as_float((r).z << 16),                       \
                          __uint_as_float((r).z & 0xffff0000u)};              \
        A[3] += (f32x2_t){__uint_as_float((r).w << 16),                       \
                          __uint_as_float((r).w & 0xffff0000u)};              \
    }

// ---------------------------------------------------------------- CSR build
__global__ void bucket_hist_k(const int* __restrict__ dst, int* __restrict__ bcnt,
                              int e, int nb) {
    __shared__ int lh[MAXB];
    int t = threadIdx.x;
    for (int i = t; i < nb; i += 256) lh[i] = 0;
    __syncthreads();
    for (int i = blockIdx.x * 256 + t; i < e; i += gridDim.x * 256)
        atomicAdd(&lh[dst[i] >> BSH], 1);
    __syncthreads();
    for (int i = t; i < nb; i += 256) {
        int c = lh[i];
        if (c) atomicAdd(&bcnt[i * 16], c);
    }
}

__global__ void bscan_k(const int* __restrict__ bcnt, int* __restrict__ boff,
                        int* __restrict__ bpos, int nb, int e) {
    __shared__ int l[MAXB];
    int t = threadIdx.x;
    l[t] = (t < nb) ? bcnt[t * 16] : 0;
    __syncthreads();
    for (int off = 1; off < MAXB; off <<= 1) {
        int v = (t >= off) ? l[t - off] : 0;
        __syncthreads();
        l[t] += v;
        __syncthreads();
    }
    int excl = (t > 0) ? l[t - 1] : 0;
    if (t < nb) { boff[t] = excl; bpos[t * 16] = excl; }
    if (t == 0) boff[nb] = e;
}

__global__ void scatter_k(const int* __restrict__ src, const int* __restrict__ dst,
                          int* __restrict__ bpos, unsigned* __restrict__ pool,
                          int e, int nb) {
    __shared__ int lh[MAXB];
    __shared__ int lcur[MAXB];
    int t = threadIdx.x;
    for (int i = t; i < nb; i += 256) lh[i] = 0;
    __syncthreads();
    int chunk = (e + gridDim.x - 1) / gridDim.x;
    int s = blockIdx.x * chunk;
    int en = min(e, s + chunk);
    for (int i = s + t; i < en; i += 256)
        atomicAdd(&lh[dst[i] >> BSH], 1);
    __syncthreads();
    for (int i = t; i < nb; i += 256) {
        int c = lh[i];
        lcur[i] = c ? atomicAdd(&bpos[i * 16], c) : 0;
    }
    __syncthreads();
    for (int i = s + t; i < en; i += 256) {
        int d = dst[i];
        int p = atomicAdd(&lcur[d >> BSH], 1);
        pool[p] = (unsigned)src[i] | ((unsigned)(d & 255) << 17);
    }
}

// fused: per-bucket node histogram + LDS exclusive scan -> rp directly
__global__ void nhist_rp_k(const unsigned* __restrict__ pool, const int* __restrict__ boff,
                           int* __restrict__ rp, int n) {
    __shared__ int lc[256];
    __shared__ int ls[256];
    int b = blockIdx.x, t = threadIdx.x;
    lc[t] = 0;
    __syncthreads();
    int s = boff[b], e = boff[b + 1];
    for (int i = s + t; i < e; i += 256) atomicAdd(&lc[pool[i] >> 17], 1);
    __syncthreads();
    int v = lc[t];
    ls[t] = v;
    __syncthreads();
    for (int off = 1; off < 256; off <<= 1) {
        int x = (t >= off) ? ls[t - off] : 0;
        __syncthreads();
        ls[t] += x;
        __syncthreads();
    }
    int excl = ls[t] - v;
    int nd = (b << BSH) + t;
    if (nd < n) rp[nd] = s + excl;
    if (nd == n - 1) rp[n] = e;
}

__global__ void cfill_k(const unsigned* __restrict__ pool, const int* __restrict__ boff,
                        const int* __restrict__ rp, int* __restrict__ col, int n) {
    __shared__ int lpos[256];
    int b = blockIdx.x, t = threadIdx.x;
    int nd = (b << BSH) + t;
    lpos[t] = (nd < n) ? rp[nd] : 0;
    __syncthreads();
    int s = boff[b], e = boff[b + 1];
    for (int i = s + t; i < e; i += 256) {
        unsigned pk = pool[i];
        int slot = atomicAdd(&lpos[pk >> 17], 1);
        col[slot] = (int)(pk & 0x1FFFFu);
    }
}

// -------------------------------------------------------------- converters
struct ConvDesc { const float* w; bf16_t* o; int kin; int kpad; };
struct ConvArgs { ConvDesc d[8]; };

__global__ void conv_w_k(ConvArgs args) {
    ConvDesc d = args.d[blockIdx.y];
    int i = blockIdx.x * 256 + threadIdx.x;
    int tot = 128 * d.kpad;
    if (i >= tot) return;
    int n = i / d.kpad, k = i - n * d.kpad;
    float v = (k < d.kin) ? d.w[(size_t)k * 128 + n] : 0.f;
    d.o[i] = (bf16_t)v;
}

__global__ void conv_x_k(const float* __restrict__ x, bf16_t* __restrict__ xb, int n) {
    int i = blockIdx.x * 256 + threadIdx.x;
    if (i >= n * 64) return;
    int node = i >> 6, k = i & 63;
    xb[i] = (k < D_IN) ? (bf16_t)x[node * D_IN + k] : (bf16_t)0.f;
}

// ------------------------------------------------------------- aggregation
// Wide-gather, index-prefetch pipelined, packed-f32 accumulate.
__global__ void agg_bf64_k(const bf16_t* __restrict__ feat, const int* __restrict__ rp,
                           const int* __restrict__ col, bf16_t* __restrict__ mean, int n) {
    int wid = (blockIdx.x * blockDim.x + threadIdx.x) >> 6;
    int lane = threadIdx.x & 63;
    if (wid >= n) return;
    int start = rp[wid], end = rp[wid + 1];
    int lc = lane & 7;
    int g = lane >> 3;
    f32x2_t accA[4], accB[4];
#pragma unroll
    for (int k = 0; k < 4; k++) { accA[k] = (f32x2_t){0.f, 0.f}; accB[k] = (f32x2_t){0.f, 0.f}; }
    int e = start + g;
    if (e + 8 < end) {
        int i0 = col[e], i1 = col[e + 8];
        for (; e + 24 < end; e += 16) {
            uint4 r0 = *(const uint4*)(feat + (size_t)i0 * 64 + lc * 8);
            uint4 r1 = *(const uint4*)(feat + (size_t)i1 * 64 + lc * 8);
            i0 = col[e + 16];
            i1 = col[e + 24];
            ACCP(r0, accA);
            ACCP(r1, accB);
        }
        uint4 r0 = *(const uint4*)(feat + (size_t)i0 * 64 + lc * 8);
        uint4 r1 = *(const uint4*)(feat + (size_t)i1 * 64 + lc * 8);
        ACCP(r0, accA);
        ACCP(r1, accB);
        e += 16;
    }
    for (; e < end; e += 8) {
        uint4 r0 = *(const uint4*)(feat + (size_t)col[e] * 64 + lc * 8);
        ACCP(r0, accA);
    }
#pragma unroll
    for (int k = 0; k < 4; k++) accA[k] += accB[k];
    float aL[4], aH[4];
#pragma unroll
    for (int k = 0; k < 4; k++) { aL[k] = accA[k].x; aH[k] = accA[k].y; }
#pragma unroll
    for (int off = 8; off < 64; off <<= 1) {
#pragma unroll
        for (int k = 0; k < 4; k++) {
            aL[k] += __shfl_xor(aL[k], off);
            aH[k] += __shfl_xor(aH[k], off);
        }
    }
    int c = end - start;
    float invc = 1.f / (float)(c > 0 ? c : 1);
    if (lane < 8) {
        bf16x8 o;
#pragma unroll
        for (int k = 0; k < 4; k++) {
            o[2 * k] = (bf16_t)(aL[k] * invc);
            o[2 * k + 1] = (bf16_t)(aH[k] * invc);
        }
        *(bf16x8*)(mean + (size_t)wid * 64 + lc * 8) = o;
    }
}

__global__ void agg_bf128_k(const bf16_t* __restrict__ feat, const int* __restrict__ rp,
                            const int* __restrict__ col, bf16_t* __restrict__ mean, int n) {
    int wid = (blockIdx.x * blockDim.x + threadIdx.x) >> 6;
    int lane = threadIdx.x & 63;
    if (wid >= n) return;
    int start = rp[wid], end = rp[wid + 1];
    int lc = lane & 15;
    int g = lane >> 4;
    f32x2_t accA[4], accB[4];
#pragma unroll
    for (int k = 0; k < 4; k++) { accA[k] = (f32x2_t){0.f, 0.f}; accB[k] = (f32x2_t){0.f, 0.f}; }
    int e = start + g;
    if (e + 4 < end) {
        int i0 = col[e], i1 = col[e + 4];
        for (; e + 12 < end; e += 8) {
            uint4 r0 = *(const uint4*)(feat + (size_t)i0 * 128 + lc * 8);
            uint4 r1 = *(const uint4*)(feat + (size_t)i1 * 128 + lc * 8);
            i0 = col[e + 8];
            i1 = col[e + 12];
            ACCP(r0, accA);
            ACCP(r1, accB);
        }
        uint4 r0 = *(const uint4*)(feat + (size_t)i0 * 128 + lc * 8);
        uint4 r1 = *(const uint4*)(feat + (size_t)i1 * 128 + lc * 8);
        ACCP(r0, accA);
        ACCP(r1, accB);
        e += 8;
    }
    for (; e < end; e += 4) {
        uint4 r0 = *(const uint4*)(feat + (size_t)col[e] * 128 + lc * 8);
        ACCP(r0, accA);
    }
#pragma unroll
    for (int k = 0; k < 4; k++) accA[k] += accB[k];
    float aL[4], aH[4];
#pragma unroll
    for (int k = 0; k < 4; k++) { aL[k] = accA[k].x; aH[k] = accA[k].y; }
#pragma unroll
    for (int off = 16; off < 64; off <<= 1) {
#pragma unroll
        for (int k = 0; k < 4; k++) {
            aL[k] += __shfl_xor(aL[k], off);
            aH[k] += __shfl_xor(aH[k], off);
        }
    }
    int c = end - start;
    float invc = 1.f / (float)(c > 0 ? c : 1);
    if (lane < 16) {
        bf16x8 o;
#pragma unroll
        for (int k = 0; k < 4; k++) {
            o[2 * k] = (bf16_t)(aL[k] * invc);
            o[2 * k + 1] = (bf16_t)(aH[k] * invc);
        }
        *(bf16x8*)(mean + (size_t)wid * 128 + lc * 8) = o;
    }
}

// ------------------------------------------------- fused SAGE linear (MFMA)
template <int KPAD, bool DUAL, bool ACC>
__global__ __launch_bounds__(256) void mfma_gemm_k(
    const bf16_t* __restrict__ A, const bf16_t* __restrict__ B,
    const bf16_t* __restrict__ WlT, const bf16_t* __restrict__ WrT,
    const float* __restrict__ bias,
    bf16_t* __restrict__ out, float2* __restrict__ partials, int M) {
    constexpr int KC = KPAD / 32;
    constexpr int WELE = 8 * KC * 64 * 8;
    __shared__ bf16_t lwl[WELE];
    __shared__ bf16_t lwr[DUAL ? WELE : 8];

    const int tid = threadIdx.x;
    for (int ch = tid; ch < 8 * KC * 64; ch += 256) {
        int nt = ch / (KC * 64);
        int rem = ch - nt * (KC * 64);
        int c = rem >> 6;
        int ln = rem & 63;
        int m = ln & 15, q = ln >> 4;
        size_t srcoff = (size_t)(nt * 16 + m) * KPAD + c * 32 + q * 8;
        *(bf16x8*)&lwl[ch * 8] = *(const bf16x8*)(WlT + srcoff);
        if (DUAL) *(bf16x8*)&lwr[ch * 8] = *(const bf16x8*)(WrT + srcoff);
    }
    __syncthreads();

    const int wid = blockIdx.x * 4 + (tid >> 6);
    const int lane = tid & 63;
    const int row0 = wid * 32;
    if (row0 >= M) return;
    const int m = lane & 15;
    const int q = lane >> 4;

    bf16x8 af[2][KC], bfr[DUAL ? 2 : 1][DUAL ? KC : 1];
#pragma unroll
    for (int s = 0; s < 2; s++) {
        const bf16_t* ar = A + (size_t)(row0 + s * 16 + m) * KPAD + q * 8;
#pragma unroll
        for (int c = 0; c < KC; c++) af[s][c] = *(const bf16x8*)(ar + c * 32);
        if (DUAL) {
            const bf16_t* br = B + (size_t)(row0 + s * 16 + m) * KPAD + q * 8;
#pragma unroll
            for (int c = 0; c < KC; c++) bfr[s][c] = *(const bf16x8*)(br + c * 32);
        }
    }

    float lsum = 0.f, lsum2 = 0.f;
#pragma unroll
    for (int nt = 0; nt < 8; nt++) {
        f32x4_t acc0 = {0.f, 0.f, 0.f, 0.f};
        f32x4_t acc1 = {0.f, 0.f, 0.f, 0.f};
#pragma unroll
        for (int c = 0; c < KC; c++) {
            bf16x8 w = *(const bf16x8*)&lwl[((nt * KC + c) * 64 + lane) * 8];
            acc0 = __builtin_amdgcn_mfma_f32_16x16x32_bf16(af[0][c], w, acc0, 0, 0, 0);
            acc1 = __builtin_amdgcn_mfma_f32_16x16x32_bf16(af[1][c], w, acc1, 0, 0, 0);
        }
        if (DUAL) {
#pragma unroll
            for (int c = 0; c < KC; c++) {
                bf16x8 w = *(const bf16x8*)&lwr[((nt * KC + c) * 64 + lane) * 8];
                acc0 = __builtin_amdgcn_mfma_f32_16x16x32_bf16(bfr[0][c], w, acc0, 0, 0, 0);
                acc1 = __builtin_amdgcn_mfma_f32_16x16x32_bf16(bfr[1][c], w, acc1, 0, 0, 0);
            }
        }
        float bv = bias ? bias[nt * 16 + m] : 0.f;
#pragma unroll
        for (int s = 0; s < 2; s++) {
            f32x4_t* ap = (s == 0) ? &acc0 : &acc1;
#pragma unroll
            for (int r = 0; r < 4; r++) {
                int row = row0 + s * 16 + q * 4 + r;
                if (row < M) {
                    float o = (*ap)[r] + bv;
                    out[(size_t)row * 128 + nt * 16 + m] = (bf16_t)o;
                    if (ACC) { lsum += o; lsum2 += o * o; }
                }
            }
        }
    }
    if (ACC) {
        for (int off = 32; off > 0; off >>= 1) {
            lsum += __shfl_down(lsum, off);
            lsum2 += __shfl_down(lsum2, off);
        }
        if (lane == 0) partials[wid] = make_float2(lsum, lsum2);
    }
}

// Layer-1 triple: PRE = mean@Wl1 + xb@Wr1 + b1 (LN partials),
// C1 = xb@Ws1, C2 = xb@Ws2. KPAD=64.
__global__ __launch_bounds__(256) void mfma_gemm3_k(
    const bf16_t* __restrict__ A, const bf16_t* __restrict__ B,
    const bf16_t* __restrict__ WlT, const bf16_t* __restrict__ WrT,
    const bf16_t* __restrict__ Ws1T, const bf16_t* __restrict__ Ws2T,
    const float* __restrict__ bias,
    bf16_t* __restrict__ outP, bf16_t* __restrict__ outC1, bf16_t* __restrict__ outC2,
    float2* __restrict__ partials, int M) {
    constexpr int KC = 2;
    constexpr int WELE = 8 * KC * 64 * 8;
    __shared__ bf16_t lwl[WELE];
    __shared__ bf16_t lwr[WELE];
    __shared__ bf16_t ls1[WELE];
    __shared__ bf16_t ls2[WELE];

    const int tid = threadIdx.x;
    for (int ch = tid; ch < 8 * KC * 64; ch += 256) {
        int nt = ch / (KC * 64);
        int rem = ch - nt * (KC * 64);
        int c = rem >> 6;
        int ln = rem & 63;
        int m = ln & 15, q = ln >> 4;
        size_t srcoff = (size_t)(nt * 16 + m) * 64 + c * 32 + q * 8;
        *(bf16x8*)&lwl[ch * 8] = *(const bf16x8*)(WlT + srcoff);
        *(bf16x8*)&lwr[ch * 8] = *(const bf16x8*)(WrT + srcoff);
        *(bf16x8*)&ls1[ch * 8] = *(const bf16x8*)(Ws1T + srcoff);
        *(bf16x8*)&ls2[ch * 8] = *(const bf16x8*)(Ws2T + srcoff);
    }
    __syncthreads();

    const int wid = blockIdx.x * 4 + (tid >> 6);
    const int lane = tid & 63;
    const int row0 = wid * 32;
    if (row0 >= M) return;
    const int m = lane & 15;
    const int q = lane >> 4;

    bf16x8 af[2][KC], bfr[2][KC];
#pragma unroll
    for (int s = 0; s < 2; s++) {
        const bf16_t* ar = A + (size_t)(row0 + s * 16 + m) * 64 + q * 8;
        const bf16_t* br = B + (size_t)(row0 + s * 16 + m) * 64 + q * 8;
#pragma unroll
        for (int c = 0; c < KC; c++) {
            af[s][c] = *(const bf16x8*)(ar + c * 32);
            bfr[s][c] = *(const bf16x8*)(br + c * 32);
        }
    }

    float lsum = 0.f, lsum2 = 0.f;
#pragma unroll
    for (int nt = 0; nt < 8; nt++) {
        f32x4_t aP0 = {0.f, 0.f, 0.f, 0.f}, aP1 = {0.f, 0.f, 0.f, 0.f};
        f32x4_t a10 = {0.f, 0.f, 0.f, 0.f}, a11 = {0.f, 0.f, 0.f, 0.f};
        f32x4_t a20 = {0.f, 0.f, 0.f, 0.f}, a21 = {0.f, 0.f, 0.f, 0.f};
#pragma unroll
        for (int c = 0; c < KC; c++) {
            int wi = ((nt * KC + c) * 64 + lane) * 8;
            bf16x8 wl = *(const bf16x8*)&lwl[wi];
            bf16x8 wr = *(const bf16x8*)&lwr[wi];
            bf16x8 w1 = *(const bf16x8*)&ls1[wi];
            bf16x8 w2 = *(const bf16x8*)&ls2[wi];
            aP0 = __builtin_amdgcn_mfma_f32_16x16x32_bf16(af[0][c], wl, aP0, 0, 0, 0);
            aP1 = __builtin_amdgcn_mfma_f32_16x16x32_bf16(af[1][c], wl, aP1, 0, 0, 0);
            aP0 = __builtin_amdgcn_mfma_f32_16x16x32_bf16(bfr[0][c], wr, aP0, 0, 0, 0);
            aP1 = __builtin_amdgcn_mfma_f32_16x16x32_bf16(bfr[1][c], wr, aP1, 0, 0, 0);
            a10 = __builtin_amdgcn_mfma_f32_16x16x32_bf16(bfr[0][c], w1, a10, 0, 0, 0);
            a11 = __builtin_amdgcn_mfma_f32_16x16x32_bf16(bfr[1][c], w1, a11, 0, 0, 0);
            a20 = __builtin_amdgcn_mfma_f32_16x16x32_bf16(bfr[0][c], w2, a20, 0, 0, 0);
            a21 = __builtin_amdgcn_mfma_f32_16x16x32_bf16(bfr[1][c], w2, a21, 0, 0, 0);
        }
        float bv = bias[nt * 16 + m];
#pragma unroll
        for (int s = 0; s < 2; s++) {
            f32x4_t* pP = (s == 0) ? &aP0 : &aP1;
            f32x4_t* p1 = (s == 0) ? &a10 : &a11;
            f32x4_t* p2 = (s == 0) ? &a20 : &a21;
#pragma unroll
            for (int r = 0; r < 4; r++) {
                int row = row0 + s * 16 + q * 4 + r;
                if (row < M) {
                    float o = (*pP)[r] + bv;
                    size_t oi = (size_t)row * 128 + nt * 16 + m;
                    outP[oi] = (bf16_t)o;
                    outC1[oi] = (bf16_t)(*p1)[r];
                    outC2[oi] = (bf16_t)(*p2)[r];
                    lsum += o; lsum2 += o * o;
                }
            }
        }
    }
    for (int off = 32; off > 0; off >>= 1) {
        lsum += __shfl_down(lsum, off);
        lsum2 += __shfl_down(lsum2, off);
    }
    if (lane == 0) partials[wid] = make_float2(lsum, lsum2);
}

__global__ void reduce_partials_k(const float2* __restrict__ p, int n,
                                  double* __restrict__ outp) {
    __shared__ double s1[256], s2[256];
    int t = threadIdx.x;
    double a = 0.0, b = 0.0;
    for (int i = t; i < n; i += 256) { a += (double)p[i].x; b += (double)p[i].y; }
    s1[t] = a; s2[t] = b;
    __syncthreads();
    for (int off = 128; off > 0; off >>= 1) {
        if (t < off) { s1[t] += s1[t + off]; s2[t] += s2[t + off]; }
        __syncthreads();
    }
    if (t == 0) { outp[0] = s1[0]; outp[1] = s2[0]; }
}

// --------------------------------------------- LN (graph mode) + PReLU (+skip)
template <int MODE>
__global__ void ln_prelu_k(const bf16_t* __restrict__ pre, const bf16_t* __restrict__ h1in,
                           const bf16_t* __restrict__ s,
                           const float* __restrict__ lnw, const float* __restrict__ lnb,
                           const float* __restrict__ a_ptr, const double* __restrict__ acc,
                           void* __restrict__ out0v, void* __restrict__ out1v, int total) {
    int i = blockIdx.x * blockDim.x + threadIdx.x;
    if (i * 4 >= total) return;
    double cinv = 1.0 / (double)total;
    double mm = acc[0] * cinv;
    double var = acc[1] * cinv - mm * mm;
    float stdv = (float)sqrt(var > 0.0 ? var : 0.0);
    float scale = 1.0f / (stdv + LN_EPS);
    float mf = (float)mm;
    float a = a_ptr[0];
    int c4 = i & 31;
    float4 w = ((const float4*)lnw)[c4];
    float4 b = ((const float4*)lnb)[c4];
    bf16x4 p4 = ((const bf16x4*)pre)[i];
    float4 h;
    h.x = ((float)p4.x - mf) * scale * w.x + b.x;
    h.y = ((float)p4.y - mf) * scale * w.y + b.y;
    h.z = ((float)p4.z - mf) * scale * w.z + b.z;
    h.w = ((float)p4.w - mf) * scale * w.w + b.w;
    h.x = h.x >= 0.f ? h.x : a * h.x;
    h.y = h.y >= 0.f ? h.y : a * h.y;
    h.z = h.z >= 0.f ? h.z : a * h.z;
    h.w = h.w >= 0.f ? h.w : a * h.w;
    if (MODE == 1) {
        bf16x4 hb;
        hb.x = (bf16_t)h.x; hb.y = (bf16_t)h.y; hb.z = (bf16_t)h.z; hb.w = (bf16_t)h.w;
        ((bf16x4*)out0v)[i] = hb;
        bf16x4 sv = ((const bf16x4*)s)[i];
        bf16x4 tb;
        tb.x = (bf16_t)(h.x + (float)sv.x); tb.y = (bf16_t)(h.y + (float)sv.y);
        tb.z = (bf16_t)(h.z + (float)sv.z); tb.w = (bf16_t)(h.w + (float)sv.w);
        ((bf16x4*)out1v)[i] = tb;
    } else if (MODE == 2) {
        bf16x4 hv = ((const bf16x4*)h1in)[i];
        bf16x4 sv = ((const bf16x4*)s)[i];
        bf16x4 tb;
        tb.x = (bf16_t)((float)hv.x + h.x + (float)sv.x);
        tb.y = (bf16_t)((float)hv.y + h.y + (float)sv.y);
        tb.z = (bf16_t)((float)hv.z + h.z + (float)sv.z);
        tb.w = (bf16_t)((float)hv.w + h.w + (float)sv.w);
        ((bf16x4*)out0v)[i] = tb;
    } else {
        ((float4*)out0v)[i] = h;
    }
}

// ------------------------------------------------------------------ launch
extern "C" void kernel_launch(void* const* d_in, const int* in_sizes, int n_in,
                              void* d_out, int out_size, void* d_ws, size_t ws_size,
                              hipStream_t stream) {
    const float* x    = (const float*)d_in[0];
    const int*   esrc = (const int*)d_in[1];
    const int*   edst = (const int*)d_in[2];
    const float* Wl1  = (const float*)d_in[3];
    const float* Wr1  = (const float*)d_in[4];
    const float* b1   = (const float*)d_in[5];
    const float* Wl2  = (const float*)d_in[6];
    const float* Wr2  = (const float*)d_in[7];
    const float* b2   = (const float*)d_in[8];
    const float* Wl3  = (const float*)d_in[9];
    const float* Wr3  = (const float*)d_in[10];
    const float* b3   = (const float*)d_in[11];
    const float* Ws1  = (const float*)d_in[12];
    const float* Ws2  = (const float*)d_in[13];
    const float* lnw1 = (const float*)d_in[14];
    const float* lnb1 = (const float*)d_in[15];
    const float* lnw2 = (const float*)d_in[16];
    const float* lnb2 = (const float*)d_in[17];
    const float* lnw3 = (const float*)d_in[18];
    const float* lnb3 = (const float*)d_in[19];
    const float* a1   = (const float*)d_in[20];
    const float* a2   = (const float*)d_in[21];
    const float* a3   = (const float*)d_in[22];

    const int N = in_sizes[0] / D_IN;
    const int E = in_sizes[1];
    const int NB = (N + 255) >> BSH;

    char* ws = (char*)d_ws;
    size_t off = 0;
    auto alloc = [&](size_t bytes) -> void* {
        void* p = ws + off;
        off += (bytes + 255) & ~(size_t)255;
        return p;
    };
    bf16_t* xb   = (bf16_t*)alloc((size_t)N * 64 * 2);
    bf16_t* mean = (bf16_t*)alloc((size_t)N * 128 * 2);
    bf16_t* PRE  = (bf16_t*)alloc((size_t)N * 128 * 2);
    bf16_t* C1   = (bf16_t*)alloc((size_t)N * 128 * 2);
    bf16_t* C2   = (bf16_t*)alloc((size_t)N * 128 * 2);
    bf16_t* h1b  = (bf16_t*)alloc((size_t)N * 128 * 2);
    bf16_t* TB   = (bf16_t*)alloc((size_t)N * 128 * 2);
    bf16_t* WT   = (bf16_t*)alloc((size_t)(4 * 128 * 64 + 4 * 128 * 128) * 2);
    int* rp   = (int*)alloc((size_t)(N + 1) * 4);
    int* col  = (int*)alloc((size_t)E * 4);
    int* bcnt = (int*)alloc((size_t)MAXB * 16 * 4);
    int* boff = (int*)alloc((size_t)(MAXB + 1) * 4);
    int* bpos = (int*)alloc((size_t)MAXB * 16 * 4);
    unsigned* pool = (unsigned*)alloc((size_t)E * 4);
    double* lnacc = (double*)alloc(6 * 8);
    const int tiles = (N + 31) / 32;
    float2* partials = (float2*)alloc((size_t)tiles * 8);

    bf16_t* Wl1T = WT;
    bf16_t* Wr1T = Wl1T + 128 * 64;
    bf16_t* Ws1T = Wr1T + 128 * 64;
    bf16_t* Ws2T = Ws1T + 128 * 64;
    bf16_t* Wl2T = Ws2T + 128 * 64;
    bf16_t* Wr2T = Wl2T + 128 * 128;
    bf16_t* Wl3T = Wr2T + 128 * 128;
    bf16_t* Wr3T = Wl3T + 128 * 128;

    hipMemsetAsync(bcnt, 0, (size_t)MAXB * 16 * 4, stream);

    // --- bucketed CSR build
    bucket_hist_k<<<256, 256, 0, stream>>>(edst, bcnt, E, NB);
    bscan_k<<<1, MAXB, 0, stream>>>(bcnt, boff, bpos, NB, E);
    scatter_k<<<256, 256, 0, stream>>>(esrc, edst, bpos, pool, E, NB);
    nhist_rp_k<<<NB, 256, 0, stream>>>(pool, boff, rp, N);
    cfill_k<<<NB, 256, 0, stream>>>(pool, boff, rp, col, N);

    // --- weight/feature conversion
    ConvArgs ca;
    ca.d[0] = {Wl1, Wl1T, 50, 64};
    ca.d[1] = {Wr1, Wr1T, 50, 64};
    ca.d[2] = {Ws1, Ws1T, 50, 64};
    ca.d[3] = {Ws2, Ws2T, 50, 64};
    ca.d[4] = {Wl2, Wl2T, 128, 128};
    ca.d[5] = {Wr2, Wr2T, 128, 128};
    ca.d[6] = {Wl3, Wl3T, 128, 128};
    ca.d[7] = {Wr3, Wr3T, 128, 128};
    conv_w_k<<<dim3(64, 8), 256, 0, stream>>>(ca);
    conv_x_k<<<(N * 64 + 255) / 256, 256, 0, stream>>>(x, xb, N);

    const int aggBlocks = ((N * 64) + 255) / 256;
    const int gemmBlocks = (tiles + 3) / 4;
    const int lnBlocks = (N * 128 / 4 + 255) / 256;
    const int total = N * 128;

    // ---- layer 1
    agg_bf64_k<<<aggBlocks, 256, 0, stream>>>(xb, rp, col, mean, N);
    mfma_gemm3_k<<<gemmBlocks, 256, 0, stream>>>(
        mean, xb, Wl1T, Wr1T, Ws1T, Ws2T, b1, PRE, C1, C2, partials, N);
    reduce_partials_k<<<1, 256, 0, stream>>>(partials, tiles, lnacc + 0);
    ln_prelu_k<1><<<lnBlocks, 256, 0, stream>>>(
        PRE, nullptr, C1, lnw1, lnb1, a1, lnacc + 0, h1b, TB, total);

    // ---- layer 2
    agg_bf128_k<<<aggBlocks, 256, 0, stream>>>(TB, rp, col, mean, N);
    mfma_gemm_k<128, true, true><<<gemmBlocks, 256, 0, stream>>>(
        mean, TB, Wl2T, Wr2T, b2, PRE, partials, N);
    reduce_partials_k<<<1, 256, 0, stream>>>(partials, tiles, lnacc + 2);
    ln_prelu_k<2><<<lnBlocks, 256, 0, stream>>>(
        PRE, h1b, C2, lnw2, lnb2, a2, lnacc + 2, TB, nullptr, total);

    // ---- layer 3
    agg_bf128_k<<<aggBlocks, 256, 0, stream>>>(TB, rp, col, mean, N);
    mfma_gemm_k<128, true, true><<<gemmBlocks, 256, 0, stream>>>(
        mean, TB, Wl3T, Wr3T, b3, PRE, partials, N);
    reduce_partials_k<<<1, 256, 0, stream>>>(partials, tiles, lnacc + 4);
    ln_prelu_k<3><<<lnBlocks, 256, 0, stream>>>(
        PRE, nullptr, nullptr, lnw3, lnb3, a3, lnacc + 4, d_out, nullptr, total);
}